// Round 6
// baseline (234.810 us; speedup 1.0000x reference)
//
#include <hip/hip_runtime.h>
#include <math.h>

#define S_LEN 4096
#define HIDN  1024
#define NH    16
#define HD    64
#define BATCH 2
#define M_TOTAL (BATCH * S_LEN)   // 8192
#define N_RKV   (3 * HIDN)        // 3072
#define CS 128
#define NC (S_LEN / CS)           // 32

typedef __attribute__((ext_vector_type(8))) _Float16 f16x8;
typedef __attribute__((ext_vector_type(4))) float f32x4;
typedef __attribute__((ext_vector_type(16))) float f32x16;
typedef __attribute__((ext_vector_type(4))) unsigned short u16x4;

// ---------- fp16 convert ----------
__device__ __forceinline__ unsigned short f2h(float x) {
    _Float16 h = (_Float16)x;
    return *(unsigned short*)&h;
}
__device__ __forceinline__ float h2f(unsigned short b) {
    _Float16 h = *(_Float16*)&b;
    return (float)h;
}

// ---------- async global->LDS, 16B per lane ----------
__device__ __forceinline__ void load_lds16(const void* g, void* l) {
    __builtin_amdgcn_global_load_lds((const __attribute__((address_space(1))) void*)g,
                                     (__attribute__((address_space(3))) void*)l, 16, 0, 0);
}

// ---------- K0: a = mean(exp(time_decay)) ----------
__global__ void k_avg_decay(const float* __restrict__ td, float* __restrict__ a_out) {
    int t = threadIdx.x;
    double acc = 0.0;
    for (int i = t; i < NH * HD; i += 64) acc += exp((double)td[i]);
    for (int off = 32; off > 0; off >>= 1) acc += __shfl_down(acc, off, 64);
    if (t == 0) a_out[0] = (float)(acc / (double)(NH * HD));
}

// ---------- K1a: mixed = hs*tm + shift(hs)*(1-tm) -> fp16 ----------
__global__ __launch_bounds__(256)
void k_split_mix(const float* __restrict__ hs, const float* __restrict__ tm,
                 unsigned short* __restrict__ Ah) {
    int g = blockIdx.x * 256 + threadIdx.x;      // over M_TOTAL * (HIDN/4)
    int kc = (g & 255) * 4;
    int m = g >> 8;
    float4 cur = *(const float4*)&hs[(size_t)m * HIDN + kc];
    float4 t4  = *(const float4*)&tm[kc];
    float4 prev = make_float4(0.f, 0.f, 0.f, 0.f);
    if (m & (S_LEN - 1)) prev = *(const float4*)&hs[(size_t)(m - 1) * HIDN + kc];
    u16x4 h;
    h.x = f2h(cur.x * t4.x + prev.x * (1.f - t4.x));
    h.y = f2h(cur.y * t4.y + prev.y * (1.f - t4.y));
    h.z = f2h(cur.z * t4.z + prev.z * (1.f - t4.z));
    h.w = f2h(cur.w * t4.w + prev.w * (1.f - t4.w));
    *(u16x4*)&Ah[(size_t)m * HIDN + kc] = h;
}

// ---------- K1b: flat fp32 -> fp16 (weights) ----------
__global__ __launch_bounds__(256)
void k_split_w(const float* __restrict__ W, unsigned short* __restrict__ Wh) {
    int g = blockIdx.x * 256 + threadIdx.x;
    size_t o = (size_t)g * 4;
    float4 v = *(const float4*)&W[o];
    u16x4 h;
    h.x = f2h(v.x); h.y = f2h(v.y); h.z = f2h(v.z); h.w = f2h(v.w);
    *(u16x4*)&Wh[o] = h;
}

__device__ __forceinline__ f32x4 mfma16(f16x8 a, f16x8 b, f32x4 c) {
    return __builtin_amdgcn_mfma_f32_16x16x32_f16(a, b, c, 0, 0, 0);
}
__device__ __forceinline__ f32x16 mfma32(f16x8 a, f16x8 b, f32x16 c) {
    return __builtin_amdgcn_mfma_f32_32x32x16_f16(a, b, c, 0, 0, 0);
}

#define SBAR  do { __builtin_amdgcn_sched_barrier(0); __builtin_amdgcn_s_barrier(); \
                   __builtin_amdgcn_sched_barrier(0); } while (0)
#define FENCE_LGKM do { __builtin_amdgcn_sched_barrier(0); \
                   asm volatile("s_waitcnt lgkmcnt(0)" ::: "memory"); \
                   __builtin_amdgcn_sched_barrier(0); } while (0)
#define VMC(n) asm volatile("s_waitcnt vmcnt(" #n ")" ::: "memory")

// ======================================================================
// GEMM1 via 32x32x16 MFMA, triple-buffered, 1 barrier / K-tile.
// rkv = Ah(8192x1024) * Wrh(3072x1024)^T -> fp16.
// BM=256 BN=384 BK=32; 512 thr = 8 waves (2M x 4N); per-wave C = 128x96
// = 4m x 3n 32x32-frags (acc 192 VGPR). Grid 32x8 = 256 blocks = 1 CU round.
//
// Why 32x32x16: one b128 fragment read feeds 32768 FLOP (2x the 16x16x32
// rate per read). Per CU per K-tile: MFMA 192x8.07=1550 cyc > LDS 112x12
// =1344 cyc -> MFMA-bound. Phases balanced: each = 7 ds_read + 12 MFMA
// (672 vs 775 cyc/CU) so both pipes overlap across the 2 waves/SIMD.
//
// Triple buffer (3 x 40KB), stage distance 2 (~3100 cyc > 900 HBM lat).
// Per wave per K-tile: 5 gload_lds (A:2 in ph1, B:3 in ph2), ONE VMC(5)
// + ONE barrier at tile end. Ledger: after tile t, in-flight = t+1(5 old)
// + t+2(5 new); VMC(5) retires t+1's -> barrier publishes them to all
// waves. WAR: stages of t+2 hit buf (t+2)%3=(t-1)%3, whose readers
// drained (FENCE_LGKM) before the t-1 barrier. Tail: t=30 VMC(0).
//
// Fragment-major LDS: stage gathers frag rows per-lane from global
// (row=lane&31, khalf=lane>>5), LDS linear; ds_read = base + lane*16,
// conflict-free by construction.
// 32x32x16 layouts: A/B row=lane&31, k=(lane>>5)*8+j;
// C/D col=lane&31 (B-side), row=(reg&3)+8*(reg>>2)+4*(lane>>5) (A-side).
// ======================================================================
__global__ __launch_bounds__(512, 2)
void k_gemm1_32(const unsigned short* __restrict__ A,
                const unsigned short* __restrict__ Bm,
                unsigned short* __restrict__ C)
{
    __shared__ unsigned short smem[61440];   // 120 KB: 3 x (A 16KB + B 24KB)
    const int tid  = threadIdx.x;
    const int lane = tid & 63;
    const int wv   = tid >> 6;               // 0..7
    const int wm = wv >> 2, wn = wv & 3;     // 2M x 4N
    const int l31 = lane & 31, lh = lane >> 5;

    // bijective XCD swizzle (256 % 8 == 0)
    const int cpx = gridDim.x >> 3;          // 32
    const int wg  = ((int)blockIdx.x & 7) * cpx + ((int)blockIdx.x >> 3);
    const int bx  = wg & 7;                  // 8 N-blocks
    const int by  = wg >> 3;                 // 32 M-blocks
    const int m0 = by * 256, n0 = bx * 384;

    // ---- staging sources (per-lane frag gather; 16B/lane)
    // A-units: u in [0,16): frag u>>1 (32 rows), kstep u&1. Wave wv owns u=2wv,2wv+1.
    // B-units: v in [0,24): frag v>>1, kstep v&1.       Wave wv owns v=3wv..3wv+2.
    const unsigned short* sA = A + (size_t)(m0 + wv * 32 + l31) * 1024 + lh * 8;
    const int v0 = 3 * wv, v1 = 3 * wv + 1, v2 = 3 * wv + 2;
    const unsigned short* sB0 = Bm + (size_t)(n0 + (v0 >> 1) * 32 + l31) * 1024 + (v0 & 1) * 16 + lh * 8;
    const unsigned short* sB1 = Bm + (size_t)(n0 + (v1 >> 1) * 32 + l31) * 1024 + (v1 & 1) * 16 + lh * 8;
    const unsigned short* sB2 = Bm + (size_t)(n0 + (v2 >> 1) * 32 + l31) * 1024 + (v2 & 1) * 16 + lh * 8;
    const int dA0 = (2 * wv) * 512;          // LDS short-offsets (linear dest)
    const int dA1 = (2 * wv + 1) * 512;
    const int dB0 = 8192 + v0 * 512;
    const int dB1 = 8192 + v1 * 512;
    const int dB2 = 8192 + v2 * 512;

#define STG_A(T, b) do { \
    load_lds16(sA + (T) * 32,      smem + (b) * 20480 + dA0); \
    load_lds16(sA + (T) * 32 + 16, smem + (b) * 20480 + dA1); } while (0)
#define STG_B(T, b) do { \
    load_lds16(sB0 + (T) * 32, smem + (b) * 20480 + dB0); \
    load_lds16(sB1 + (T) * 32, smem + (b) * 20480 + dB1); \
    load_lds16(sB2 + (T) * 32, smem + (b) * 20480 + dB2); } while (0)

    // ---- read bases (bytes): frag-major, base + lane*16 contiguous
    const int aRd = wm * 8192 + lane * 16;           // + mf*2048 + ks*1024
    const int bRd = 16384 + wn * 6144 + lane * 16;   // + nf*2048 + ks*1024

    f16x8 aF[4], bF[3];
    f32x16 acc[4][3] = {};

#define RD(b, ks) { const char* p_ = (const char*)smem + (b) * 40960; \
    _Pragma("unroll") for (int mf = 0; mf < 4; ++mf) \
        aF[mf] = *(const f16x8*)(p_ + aRd + mf * 2048 + (ks) * 1024); \
    _Pragma("unroll") for (int nf = 0; nf < 3; ++nf) \
        bF[nf] = *(const f16x8*)(p_ + bRd + nf * 2048 + (ks) * 1024); }

#define MM() { __builtin_amdgcn_s_setprio(1); \
    _Pragma("unroll") for (int mf = 0; mf < 4; ++mf) \
    _Pragma("unroll") for (int nf = 0; nf < 3; ++nf) \
        acc[mf][nf] = mfma32(aF[mf], bF[nf], acc[mf][nf]); \
    __builtin_amdgcn_s_setprio(0); }

    // ---- prologue: tiles 0,1 fully staged; VMC(5) retires tile0; publish
    STG_A(0, 0); STG_B(0, 0);
    STG_A(1, 1); STG_B(1, 1);
    VMC(5);
    SBAR;

    int bf = 0;
    for (int t = 0; t < 32; ++t) {
        int bs = bf + 2; if (bs >= 3) bs -= 3;
        const bool st = (t < 30);
        // phase 1: k-step 0 (7 ds_read + 12 MFMA); stage t+2's A-units
        RD(bf, 0);
        if (st) { STG_A(t + 2, bs); }
        FENCE_LGKM;
        MM();
        // phase 2: k-step 1; stage t+2's B-units
        RD(bf, 1);
        if (st) { STG_B(t + 2, bs); }
        FENCE_LGKM;
        MM();
        if (st) { VMC(5); } else { VMC(0); }
        SBAR;
        bf += 1; if (bf == 3) bf = 0;
    }

    // ---- epilogue: fp16 C write (32x32 C/D layout)
#pragma unroll
    for (int mf = 0; mf < 4; ++mf)
#pragma unroll
        for (int nf = 0; nf < 3; ++nf) {
            int col = n0 + wn * 96 + nf * 32 + l31;
#pragma unroll
            for (int reg = 0; reg < 16; ++reg) {
                int row = m0 + wm * 128 + mf * 32 + (reg & 3) + 8 * (reg >> 2) + 4 * lh;
                C[(size_t)row * N_RKV + col] = f2h(acc[mf][nf][reg]);
            }
        }
}

// ---------- GEMM2: 128x128 dbuf MFMA GEMM (unchanged, proven) ----------
template<int LDC, int NBX, bool HALF_OUT>
__global__ __launch_bounds__(256, 2)
void k_gemm_bt(const unsigned short* __restrict__ A,
               const unsigned short* __restrict__ Bm,
               void* __restrict__ Cv)
{
    __shared__ unsigned short smem[16384];       // 32 KB: two 8192-elem buffers
    const int tid  = threadIdx.x;
    const int lane = tid & 63;
    const int wave = tid >> 6;
    const int wm = wave >> 1, wn = wave & 1;

    const int cpx = gridDim.x >> 3;
    const int wg  = (blockIdx.x & 7) * cpx + (blockIdx.x >> 3);
    const int bx  = wg % NBX;
    const int by  = wg / NBX;
    const int m0 = by * 128;
    const int n0 = bx * 128;

    const unsigned short* segsrc[4];
    int segdst[4];
    {
        int rowoff = lane >> 2;
        int q = (lane & 3) ^ (rowoff & 3);
#pragma unroll
        for (int i = 0; i < 4; ++i) {
            int s = wave * 4 + i;
            const unsigned short* base = (s < 8) ? A : Bm;
            int row = (s < 8) ? (m0 + s * 16) : (n0 + (s - 8) * 16);
            segsrc[i] = base + (size_t)(row + rowoff) * 1024 + q * 8;
            segdst[i] = s * 512;
        }
    }

    const int lm = lane & 15;
    const int rq = lane >> 4;
    const int qx = rq ^ (lane & 3);
    int aoff[4], boff2[4];
#pragma unroll
    for (int t = 0; t < 4; ++t) {
        aoff[t]  = (wm * 64 + t * 16 + lm) * 32 + qx * 8;
        boff2[t] = 4096 + (wn * 64 + t * 16 + lm) * 32 + qx * 8;
    }

    f32x4 acc[4][4] = {};

#pragma unroll
    for (int i = 0; i < 4; ++i) load_lds16(segsrc[i], smem + segdst[i]);

    int p = 0;
    for (int kt = 0; kt < 1024; kt += 32) {
        __syncthreads();
        if (kt + 32 < 1024) {
#pragma unroll
            for (int i = 0; i < 4; ++i)
                load_lds16(segsrc[i] + kt + 32, smem + ((p ^ 1) * 8192 + segdst[i]));
        }
        const unsigned short* sb = smem + p * 8192;
        f16x8 fah[4], fb[4];
#pragma unroll
        for (int t = 0; t < 4; ++t) {
            fah[t] = *(const f16x8*)(sb + aoff[t]);
            fb[t]  = *(const f16x8*)(sb + boff2[t]);
        }
#pragma unroll
        for (int mt = 0; mt < 4; ++mt)
#pragma unroll
            for (int nt = 0; nt < 4; ++nt)
                acc[mt][nt] = mfma16(fah[mt], fb[nt], acc[mt][nt]);
        p ^= 1;
    }

#pragma unroll
    for (int mt = 0; mt < 4; ++mt)
#pragma unroll
        for (int nt = 0; nt < 4; ++nt) {
            int col = n0 + wn * 64 + nt * 16 + lm;
#pragma unroll
            for (int r = 0; r < 4; ++r) {
                int row = m0 + wm * 64 + mt * 16 + rq * 4 + r;
                if constexpr (HALF_OUT)
                    ((unsigned short*)Cv)[(size_t)row * LDC + col] = f2h(acc[mt][nt][r]);
                else
                    ((float*)Cv)[(size_t)row * LDC + col] = acc[mt][nt][r];
            }
        }
}

// ---------- K3: chunk decay sums Cb from rkv (RoPE'd k * v) ----------
__global__ __launch_bounds__(256)
void k_cb(const unsigned short* __restrict__ rkv,
          const float* __restrict__ cosp, const float* __restrict__ sinp,
          const float* __restrict__ a_ptr, float* __restrict__ Cb)
{
    __shared__ float Ls[4][64][4];
    int bid = blockIdx.x;                        // bh*NC + c
    int c  = bid & (NC - 1);
    int bh = bid >> 5;
    int b = bh >> 4, h = bh & 15;
    int lane = threadIdx.x & 63;
    int wave = threadIdx.x >> 6;
    int lm = lane & 15;
    int rs = lane >> 4;
    int d0 = lm * 4;
    float a = a_ptr[0];
    float sgn = (lm < 8) ? -1.f : 1.f;
    float ps0 = 0.f, ps1 = 0.f, ps2 = 0.f, ps3 = 0.f;
#pragma unroll
    for (int it = 0; it < 8; ++it) {
        int t = wave * 32 + it * 4 + rs;         // in-chunk row 0..127
        int s = c * CS + t;
        const unsigned short* rk = rkv + ((size_t)b * S_LEN + s) * N_RKV + h * 64 + d0;
        u16x4 k4 = *(const u16x4*)(rk + 1024);
        u16x4 v4 = *(const u16x4*)(rk + 2048);
        float4 cs4 = *(const float4*)&cosp[s * HD + d0];
        float4 sn4 = *(const float4*)&sinp[s * HD + d0];
        float e = expf(a * (float)t);
        float k0 = h2f(k4.x), k1 = h2f(k4.y), k2 = h2f(k4.z), k3 = h2f(k4.w);
        float kp0 = __shfl_xor(k0, 8, 64);
        float kp1 = __shfl_xor(k1, 8, 64);
        float kp2 = __shfl_xor(k2, 8, 64);
        float kp3 = __shfl_xor(k3, 8, 64);
        ps0 += e * (k0 * cs4.x + sgn * kp0 * sn4.x) * h2f(v4.x);
        ps1 += e * (k1 * cs4.y + sgn * kp1 * sn4.y) * h2f(v4.y);
        ps2 += e * (k2 * cs4.z + sgn * kp2 * sn4.z) * h2f(v4.z);
        ps3 += e * (k3 * cs4.w + sgn * kp3 * sn4.w) * h2f(v4.w);
    }
    Ls[wave][lane][0] = ps0; Ls[wave][lane][1] = ps1;
    Ls[wave][lane][2] = ps2; Ls[wave][lane][3] = ps3;
    __syncthreads();
    if (threadIdx.x < 64) {
        int d = threadIdx.x;
        int lmm = d >> 2, j = d & 3;
        float sum = 0.f;
#pragma unroll
        for (int wvv = 0; wvv < 4; ++wvv)
#pragma unroll
            for (int r = 0; r < 4; ++r)
                sum += Ls[wvv][r * 16 + lmm][j];
        Cb[((size_t)bh * NC + c) * 64 + d] = sum;
    }
}

// ---------- K5: exclusive chunk suffix ----------
__global__ __launch_bounds__(64)
void k_chunk_suffix(const float* __restrict__ Cb, const float* __restrict__ a_ptr,
                    float* __restrict__ Sb) {
    int bh = blockIdx.x;
    int d = threadIdx.x;
    float a = a_ptr[0];
    float eaCS = expf(a * (float)CS);
    float run = 0.f;
    Sb[(size_t)(bh * NC + NC - 1) * 64 + d] = 0.f;
    for (int c = NC - 2; c >= 0; --c) {
        run = Cb[(size_t)(bh * NC + c + 1) * 64 + d] + eaCS * run;
        Sb[(size_t)(bh * NC + c) * 64 + d] = run;
    }
}

// ---------- K5b: reciprocal normalizer table 1/Z ----------
__global__ __launch_bounds__(256)
void k_ztab(const float* __restrict__ a_ptr, float* __restrict__ Zt) {
    int i = blockIdx.x * 256 + threadIdx.x;
    if (i < S_LEN) {
        float a = a_ptr[0];
        float em1a = expm1f(a);
        Zt[i] = 1.f / (expm1f(a * (float)(S_LEN - i)) / em1a + 1e-8f);
    }
}

// ---------- K6: in-chunk suffix scan + epilogue, LDS-staged chunk tile ----------
__global__ __launch_bounds__(256)
void k_wkv2(const unsigned short* __restrict__ rkv,
            const float* __restrict__ cosp, const float* __restrict__ sinp,
            const float* __restrict__ Sb, const float* __restrict__ a_ptr,
            const float* __restrict__ tf, const float* __restrict__ Zt,
            unsigned short* __restrict__ outH) {
    __shared__ unsigned short L[3 * 128 * 64];   // 48 KB: r,k,v tiles [row][d]
    __shared__ float Tl[4][64];
    int bid = blockIdx.x;                // bh*NC + c
    int c  = bid & (NC - 1);
    int bh = bid >> 5;
    int b = bh >> 4, h = bh & 15;
    int lane = threadIdx.x & 63;
    int wave = threadIdx.x >> 6;
    int s0 = c * CS;

#pragma unroll
    for (int i = 0; i < 12; ++i) {
        int seg = wave * 12 + i;         // 0..47
        int stream = seg >> 4;           // 0=r 1=k 2=v
        int rg = seg & 15;               // 8-row group
        int row = rg * 8 + (lane >> 3);
        const unsigned short* src = rkv
            + ((size_t)b * S_LEN + s0 + row) * N_RKV + stream * 1024 + h * 64
            + (lane & 7) * 8;
        load_lds16(src, L + stream * 8192 + rg * 512);
    }
    __syncthreads();

    float a = a_ptr[0];
    float ea = expf(a);
    const unsigned short* Lr = L;
    const unsigned short* Lk = L + 8192;
    const unsigned short* Lv = L + 16384;
    float sgn = (lane < 32) ? -1.f : 1.f;
    int lx = lane ^ 32;

    float kvreg[32], rreg[32];
    float w = 1.f, T = 0.f;
#pragma unroll
    for (int t = 0; t < 32; ++t) {
        int row = wave * 32 + t;
        float r_ = h2f(Lr[row * 64 + lane]);
        float k_ = h2f(Lk[row * 64 + lane]);
        float kp = h2f(Lk[row * 64 + lx]);
        float v_ = h2f(Lv[row * 64 + lane]);
        float cs = cosp[(s0 + row) * HD + lane];
        float sn = sinp[(s0 + row) * HD + lane];
        float sig = 1.f / (1.f + expf(-r_));
        float sigp = __shfl_xor(sig, 32, 64);
        rreg[t]  = sig * cs + sgn * sigp * sn;
        kvreg[t] = (k_ * cs + sgn * kp * sn) * v_;
        T += w * kvreg[t];
        w *= ea;
    }
    Tl[wave][lane] = T;
    __syncthreads();

    float e32 = expf(a * 32.f);
    float S_run = Sb[(size_t)bid * 64 + lane] * expf(a * 32.f * (float)(3 - wave));
    float f = 1.f;
    for (int wp = wave + 1; wp < 4; ++wp) {
        S_run += f * Tl[wp][lane];
        f *= e32;
    }
    float tfv = tf[h * HD + lane];
#pragma unroll
    for (int t = 31; t >= 0; --t) {
        float kv = kvreg[t];
        S_run = kv + ea * S_run;
        int ig = s0 + wave * 32 + t;
        float o = rreg[t] * (tfv * kv + S_run * Zt[ig]);
        size_t m = (size_t)b * S_LEN + ig;
        outH[m * HIDN + h * HD + lane] = f2h(o);
    }
}

extern "C" void kernel_launch(void* const* d_in, const int* in_sizes, int n_in,
                              void* d_out, int out_size, void* d_ws, size_t ws_size,
                              hipStream_t stream) {
    const float* hs    = (const float*)d_in[0];
    const float* cosp  = (const float*)d_in[1];
    const float* sinp  = (const float*)d_in[2];
    const float* W_rkv = (const float*)d_in[3];
    const float* W_o   = (const float*)d_in[4];
    const float* td    = (const float*)d_in[5];
    const float* tf    = (const float*)d_in[6];
    const float* tm    = (const float*)d_in[7];
    float* out = (float*)d_out;

    // workspace layout (total 76,021,764 B — unchanged footprint)
    char* w = (char*)d_ws;
    unsigned short* rkvH = (unsigned short*)w;                    // 48 MiB [gemm1 -> cb,wkv2]
    unsigned short* Ah   = (unsigned short*)(w + 50331648);       // 16 MiB [mix -> gemm1]
    unsigned short* outH = (unsigned short*)(w + 50331648);       // aliases Ah (dead after gemm1)
    unsigned short* Wrh  = (unsigned short*)(w + 67108864);       // 6 MiB
    unsigned short* Woh  = (unsigned short*)(w + 73400320);       // 2 MiB
    float*          Cb   = (float*)(w + 75497472);                // 256 KiB
    float*          Sb   = (float*)(w + 75759616);                // 256 KiB
    float*          a_ptr= (float*)(w + 76021760);                // 4 B
    float*          Zt   = Cb;   // 16 KiB table; Cb dead after k_chunk_suffix

    k_avg_decay<<<1, 64, 0, stream>>>(td, a_ptr);

    k_split_mix<<<(M_TOTAL * HIDN / 4) / 256, 256, 0, stream>>>(hs, tm, Ah);
    k_split_w<<<(N_RKV * HIDN / 4) / 256, 256, 0, stream>>>(W_rkv, Wrh);
    k_split_w<<<(HIDN * HIDN / 4) / 256, 256, 0, stream>>>(W_o, Woh);

    // GEMM1: 32x32-MFMA triple-buffered 256x384, 256 blocks = 1 CU round
    k_gemm1_32<<<256, 512, 0, stream>>>(Ah, Wrh, rkvH);

    k_cb<<<BATCH * NH * NC, 256, 0, stream>>>(rkvH, cosp, sinp, a_ptr, Cb);
    k_chunk_suffix<<<BATCH * NH, 64, 0, stream>>>(Cb, a_ptr, Sb);
    k_ztab<<<S_LEN / 256, 256, 0, stream>>>(a_ptr, Zt);
    k_wkv2<<<BATCH * NH * NC, 256, 0, stream>>>(rkvH, cosp, sinp, Sb, a_ptr, tf, Zt, outH);

    // GEMM2: out = outH(8192x1024) * Woh(1024x1024)^T -> fp32
    k_gemm_bt<HIDN, 8, false><<<512, 256, 0, stream>>>(outH, Woh, out);
}